// Round 3
// baseline (1786.312 us; speedup 1.0000x reference)
//
#include <hip/hip_runtime.h>
#include <hip/hip_bf16.h>

// LagLlama forward. Runtime input-dtype detection (fp32 vs bf16); all inputs
// normalized to bf16 in ws; fp32 residual stream; output dtype follows input.
// B=2 T=1024 C=1024 NH=16 DH=64 L=4 HFF=2816

#define B_   2
#define T_   1024
#define C_   1024
#define NH_  16
#define DH_  64
#define L_   4
#define HFF_ 2816
#define EPS_ 1e-5f

typedef unsigned short u16;
typedef short bf16x8 __attribute__((ext_vector_type(8)));
typedef float f32x4 __attribute__((ext_vector_type(4)));

__device__ __forceinline__ float b2f(u16 u) {
    union { unsigned int i; float f; } v; v.i = ((unsigned int)u) << 16; return v.f;
}
__device__ __forceinline__ u16 f2b(float f) {
    union { unsigned int i; float f; } v; v.f = f;
    unsigned int r = (v.i + 0x7fff + ((v.i >> 16) & 1)) >> 16;
    return (u16)r;
}

// Detect input dtype from x's raw words. bf16 data: low u16 of each u32 is a
// bf16 of ~N(0,1) -> exponent byte in [0x70,0x87]. fp32 data: low u16 is
// mantissa bits -> exponent byte ~uniform. flag: 0 = bf16, 1 = fp32.
__global__ void detect_k(const unsigned int* __restrict__ xw, int* __restrict__ flag)
{
    int tid = threadIdx.x;
    int cnt = 0;
#pragma unroll
    for (int i = 0; i < 4; ++i) {
        unsigned int w = xw[tid * 4 + i];
        unsigned int e = (w >> 7) & 0xFF;
        if (e >= 0x70 && e <= 0x87) cnt++;
    }
#pragma unroll
    for (int off = 32; off; off >>= 1) cnt += __shfl_down(cnt, off);
    if (tid == 0) flag[0] = (cnt > 128) ? 0 : 1;
}

// Normalize one tensor to bf16.
__global__ void cvt_k(const void* __restrict__ src, u16* __restrict__ dst,
                      int n, const int* __restrict__ flag)
{
    int f = flag[0];
    int i = blockIdx.x * 256 + threadIdx.x;
    int stride = gridDim.x * 256;
    if (f) {
        const float* s = (const float*)src;
        for (; i < n; i += stride) dst[i] = f2b(s[i]);
    } else {
        const u16* s = (const u16*)src;
        for (; i < n; i += stride) dst[i] = s[i];
    }
}

// ---------------------------------------------------------------------------
// Batched GEMM: C[m,n] = sum_k A[m,k] * B[n,k]   (A: MxK lda, B: NxK ldb)
// MODE 0: write bf16 to Cb.  MODE 1: Cf[m,n] += acc (fp32 residual add).
// Batch z: bb=z/nhDiv, hh=z%nhDiv; per-operand offsets bb*s?b + hh*s?h (elems).
// M multiple of 128; K multiple of 32; N arbitrary (clamp + masked stores).
// ---------------------------------------------------------------------------
template<int MODE>
__global__ __launch_bounds__(256, 2)
void gemm_bt(const u16* __restrict__ A, const u16* __restrict__ Bm,
             u16* __restrict__ Cb, float* __restrict__ Cf,
             int M, int N, int K, int lda, int ldb, int ldc,
             int nhDiv, long sAb, long sAh, long sBb, long sBh,
             long sCb, long sCh)
{
    __shared__ __align__(16) u16 tA[128 * 32];
    __shared__ __align__(16) u16 tB[128 * 32];

    const int z  = blockIdx.z;
    const int bb = z / nhDiv;
    const int hh = z - bb * nhDiv;
    const u16* Ab = A + bb * sAb + hh * sAh;
    const u16* Bb = Bm + bb * sBb + hh * sBh;
    const long cOff = bb * sCb + hh * sCh;

    const int row0 = blockIdx.y * 128;
    const int col0 = blockIdx.x * 128;
    const int tid  = threadIdx.x;
    const int lane = tid & 63;
    const int wave = tid >> 6;
    const int wr = wave >> 1, wc = wave & 1;   // 2x2 waves of 64x64
    const int lrow = lane & 15;                // MFMA row/col within 16
    const int kg   = lane >> 4;                // k-group (0..3)

    int r_[2], cg_[2];
#pragma unroll
    for (int i = 0; i < 2; ++i) {
        int chunk = i * 256 + tid;
        r_[i]  = chunk >> 2;
        cg_[i] = chunk & 3;
    }

    f32x4 acc[4][4] = {};

    for (int k0 = 0; k0 < K; k0 += 32) {
        bf16x8 ra[2], rb[2];
#pragma unroll
        for (int i = 0; i < 2; ++i) {
            const u16* ga = Ab + (long)(row0 + r_[i]) * lda + (k0 + cg_[i] * 8);
            ra[i] = *(const bf16x8*)ga;
            int rB = col0 + r_[i]; if (rB > N - 1) rB = N - 1;   // N-tail clamp
            const u16* gb = Bb + (long)rB * ldb + (k0 + cg_[i] * 8);
            rb[i] = *(const bf16x8*)gb;
        }
        __syncthreads();
#pragma unroll
        for (int i = 0; i < 2; ++i) {
            int chunk = i * 256 + tid;
            *(bf16x8*)&tA[(size_t)chunk * 8] = ra[i];
            *(bf16x8*)&tB[(size_t)chunk * 8] = rb[i];
        }
        __syncthreads();

        bf16x8 af[4], bfr[4];
#pragma unroll
        for (int ti = 0; ti < 4; ++ti)
            af[ti] = *(const bf16x8*)&tA[(wr * 64 + ti * 16 + lrow) * 32 + kg * 8];
#pragma unroll
        for (int tj = 0; tj < 4; ++tj)
            bfr[tj] = *(const bf16x8*)&tB[(wc * 64 + tj * 16 + lrow) * 32 + kg * 8];
#pragma unroll
        for (int ti = 0; ti < 4; ++ti)
#pragma unroll
            for (int tj = 0; tj < 4; ++tj)
                acc[ti][tj] = __builtin_amdgcn_mfma_f32_16x16x32_bf16(
                    af[ti], bfr[tj], acc[ti][tj], 0, 0, 0);
    }

    const int rbase = row0 + wr * 64;
    const int cbase = col0 + wc * 64 + lrow;
#pragma unroll
    for (int ti = 0; ti < 4; ++ti) {
#pragma unroll
        for (int r = 0; r < 4; ++r) {
            int row = rbase + ti * 16 + kg * 4 + r;
#pragma unroll
            for (int tj = 0; tj < 4; ++tj) {
                int col = cbase + tj * 16;
                if (col < N) {
                    long off = cOff + (long)row * ldc + col;
                    if (MODE == 0) Cb[off] = f2b(acc[ti][tj][r]);
                    else           Cf[off] += acc[ti][tj][r];
                }
            }
        }
    }
}

// h[bt,c] = sum_f x[bt,f] * w_in[c,f]   (K=9, fp32 out)
__global__ void input_proj_k(const u16* __restrict__ x, const u16* __restrict__ w,
                             float* __restrict__ h)
{
    int idx = blockIdx.x * 256 + threadIdx.x;      // 2M
    int bt = idx >> 10, c = idx & 1023;
    float s = 0.f;
#pragma unroll
    for (int f = 0; f < 9; ++f) s += b2f(x[bt * 9 + f]) * b2f(w[c * 9 + f]);
    h[idx] = s;
}

// out[row,:] = h[row,:] * rsqrt(mean(h^2)+eps) * g.
// isFinal && flag: write fp32, else bf16.
__global__ void rms_k(const float* __restrict__ h, const u16* __restrict__ g,
                      void* __restrict__ out, int isFinal,
                      const int* __restrict__ flag)
{
    __shared__ float red[8];
    const int row = blockIdx.x;
    const float* hr = h + (size_t)row * C_;
    float ss = 0.f;
    for (int c = threadIdx.x; c < C_; c += 256) { float v = hr[c]; ss += v * v; }
#pragma unroll
    for (int off = 32; off; off >>= 1) ss += __shfl_down(ss, off);
    int lane = threadIdx.x & 63, wave = threadIdx.x >> 6;
    if (lane == 0) red[wave] = ss;
    __syncthreads();
    if (threadIdx.x == 0)
        red[4] = rsqrtf((red[0] + red[1] + red[2] + red[3]) / (float)C_ + EPS_);
    __syncthreads();
    float r = red[4];
    const int f32out = isFinal && flag[0];
    for (int c = threadIdx.x; c < C_; c += 256) {
        float val = hr[c] * r * b2f(g[c]);
        size_t o = (size_t)row * C_ + c;
        if (f32out) ((float*)out)[o] = val;
        else        ((u16*)out)[o]   = f2b(val);
    }
}

// RoPE in place on q [b,t,h*64+d] and the k-half of kv [b,t,(0:1024)]
__global__ void rope_k(u16* __restrict__ q, u16* __restrict__ kv)
{
    int idx = blockIdx.x * 256 + threadIdx.x;      // B*T*NH*32 = 1M
    int i = idx & 31;
    int hh = (idx >> 5) & 15;
    int t = (idx >> 9) & 1023;
    int b = idx >> 19;
    float invf = powf(10000.0f, -(float)i / 32.0f);
    float fr = (float)t * invf;
    float cf = cosf(fr), sf = sinf(fr);

    size_t qo = ((size_t)(b * 1024 + t) << 10) + hh * 64 + i;
    float x1 = b2f(q[qo]), x2 = b2f(q[qo + 32]);
    q[qo]      = f2b(x1 * cf - x2 * sf);
    q[qo + 32] = f2b(x2 * cf + x1 * sf);

    size_t ko = ((size_t)(b * 1024 + t) << 11) + hh * 64 + i;
    x1 = b2f(kv[ko]); x2 = b2f(kv[ko + 32]);
    kv[ko]      = f2b(x1 * cf - x2 * sf);
    kv[ko + 32] = f2b(x2 * cf + x1 * sf);
}

// vt[b,h,d,s] = kv[b,s, C + h*64 + d]
__global__ void vtrans_k(const u16* __restrict__ kv, u16* __restrict__ vt)
{
    int idx = blockIdx.x * 256 + threadIdx.x;      // 2M
    int s = idx & 1023;
    int d = (idx >> 10) & 63;
    int hh = (idx >> 16) & 15;
    int b = idx >> 20;
    vt[idx] = kv[((size_t)(b * 1024 + s) << 11) + 1024 + hh * 64 + d];
}

// causal softmax row (z,t) in place on bf16 scores; scale=0.125 folded in.
// cols > t written as exact 0 so PV can run full-K.  z over 16 heads.
__global__ void softmax_k(u16* __restrict__ S)
{
    __shared__ float red[8];
    const int t = blockIdx.x & 1023;
    const int z = blockIdx.x >> 10;
    u16* row = S + ((size_t)z << 20) + ((size_t)t << 10);
    const int n = t + 1;
    const int tid = threadIdx.x;
    const int lane = tid & 63, wave = tid >> 6;

    float mx = -1e30f;
    for (int c = tid; c < n; c += 256) mx = fmaxf(mx, 0.125f * b2f(row[c]));
#pragma unroll
    for (int off = 32; off; off >>= 1) mx = fmaxf(mx, __shfl_down(mx, off));
    if (lane == 0) red[wave] = mx;
    __syncthreads();
    if (tid == 0) red[4] = fmaxf(fmaxf(red[0], red[1]), fmaxf(red[2], red[3]));
    __syncthreads();
    const float M = red[4];

    float sum = 0.f;
    for (int c = tid; c < n; c += 256) sum += __expf(0.125f * b2f(row[c]) - M);
#pragma unroll
    for (int off = 32; off; off >>= 1) sum += __shfl_down(sum, off);
    if (lane == 0) red[wave] = sum;
    __syncthreads();
    if (tid == 0) red[5] = red[0] + red[1] + red[2] + red[3];
    __syncthreads();
    const float inv = 1.0f / red[5];

    for (int c = tid; c < 1024; c += 256) {
        float p = (c < n) ? __expf(0.125f * b2f(row[c]) - M) * inv : 0.f;
        row[c] = f2b(p);
    }
}

// u1 = silu(u1) * u2
__global__ void silu_mul_k(u16* __restrict__ u1, const u16* __restrict__ u2)
{
    size_t idx = (size_t)blockIdx.x * 256 + threadIdx.x;   // 2048*2816
    float a = b2f(u1[idx]);
    float m = a / (1.f + __expf(-a));
    u1[idx] = f2b(m * b2f(u2[idx]));
}

// ---------------------------------------------------------------------------
static inline void launch_gemm(bool add, const u16* A, const u16* Bm, void* C,
                               int M, int N, int K, int lda, int ldb, int ldc,
                               int batch, int nhDiv,
                               long sAb, long sAh, long sBb, long sBh,
                               long sCb, long sCh, hipStream_t stream)
{
    dim3 g((N + 127) / 128, M / 128, batch);
    if (add)
        gemm_bt<1><<<g, 256, 0, stream>>>(A, Bm, nullptr, (float*)C,
            M, N, K, lda, ldb, ldc, nhDiv, sAb, sAh, sBb, sBh, sCb, sCh);
    else
        gemm_bt<0><<<g, 256, 0, stream>>>(A, Bm, (u16*)C, nullptr,
            M, N, K, lda, ldb, ldc, nhDiv, sAb, sAh, sBb, sBh, sCb, sCh);
}

extern "C" void kernel_launch(void* const* d_in, const int* in_sizes, int n_in,
                              void* d_out, int out_size, void* d_ws, size_t ws_size,
                              hipStream_t stream)
{
    char* w = (char*)d_ws;
    float* h  = (float*)w;                           // [0,8) MB fp32 residual
    u16* a    = (u16*)(w + (8u  << 20));             // [8,12)
    u16* q    = (u16*)(w + (12u << 20));             // [12,16)
    u16* kv   = (u16*)(w + (16u << 20));             // [16,24)
    u16* vt   = (u16*)(w + (24u << 20));             // [24,28)
    u16* y    = (u16*)(w + (28u << 20));             // [28,32)
    u16* S    = (u16*)(w + (32u << 20));             // [32,64)  16 heads x 1M
    u16* u1   = S;                                   // MLP overlaps S lifetime
    u16* u2   = S + (size_t)2048 * HFF_;

    // bf16-normalized input copies above 64 MB
    size_t off = (size_t)64 << 20;
    const int nelem[11] = {
        B_ * T_ * 9,            // x
        C_ * 9,                 // w_in
        L_ * C_ * C_,           // wq
        L_ * 2 * C_ * C_,       // wkv
        L_ * C_ * C_,           // wo
        L_ * HFF_ * C_,         // w1
        L_ * HFF_ * C_,         // w2
        L_ * C_ * HFF_,         // w3
        L_ * C_,                // g1
        L_ * C_,                // g2
        C_                      // gf
    };
    u16* cbuf[11];
    for (int i = 0; i < 11; ++i) {
        cbuf[i] = (u16*)(w + off);
        off += ((size_t)nelem[i] * 2 + 255) & ~(size_t)255;
    }
    int* flag = (int*)(w + off);

    detect_k<<<1, 64, 0, stream>>>((const unsigned int*)d_in[0], flag);
    for (int i = 0; i < 11; ++i) {
        int blocks = (nelem[i] + 255) / 256; if (blocks > 2048) blocks = 2048;
        cvt_k<<<blocks, 256, 0, stream>>>(d_in[i], cbuf[i], nelem[i], flag);
    }
    const u16* cx   = cbuf[0];
    const u16* cwin = cbuf[1];
    const u16* cwq  = cbuf[2];
    const u16* cwkv = cbuf[3];
    const u16* cwo  = cbuf[4];
    const u16* cw1  = cbuf[5];
    const u16* cw2  = cbuf[6];
    const u16* cw3  = cbuf[7];
    const u16* cg1  = cbuf[8];
    const u16* cg2  = cbuf[9];
    const u16* cgf  = cbuf[10];

    const long TC  = (long)T_ * C_;      // 1M
    const long T2C = 2 * TC;
    const long TT  = (long)T_ * T_;      // 1M

    input_proj_k<<<8192, 256, 0, stream>>>(cx, cwin, h);

    for (int l = 0; l < L_; ++l) {
        const u16* wq_l  = cwq  + (size_t)l * C_ * C_;
        const u16* wkv_l = cwkv + (size_t)l * 2 * C_ * C_;
        const u16* wo_l  = cwo  + (size_t)l * C_ * C_;
        const u16* w1_l  = cw1  + (size_t)l * HFF_ * C_;
        const u16* w2_l  = cw2  + (size_t)l * HFF_ * C_;
        const u16* w3_l  = cw3  + (size_t)l * C_ * HFF_;

        // --- attention ---
        rms_k<<<2048, 256, 0, stream>>>(h, cg1 + l * C_, a, 0, flag);
        launch_gemm(false, a, wq_l, q, 2048, 1024, 1024, 1024, 1024, 1024,
                    1, 1, 0, 0, 0, 0, 0, 0, stream);
        launch_gemm(false, a, wkv_l, kv, 2048, 2048, 1024, 1024, 1024, 2048,
                    1, 1, 0, 0, 0, 0, 0, 0, stream);
        rope_k<<<4096, 256, 0, stream>>>(q, kv);
        vtrans_k<<<8192, 256, 0, stream>>>(kv, vt);

        for (int b = 0; b < B_; ++b) {    // per-batch attention (S = 32 MB)
            const u16* qb  = q  + (size_t)b * TC;
            const u16* kvb = kv + (size_t)b * T2C;
            const u16* vtb = vt + (size_t)b * NH_ * DH_ * T_;
            u16* yb        = y  + (size_t)b * TC;
            launch_gemm(false, qb, kvb, S, 1024, 1024, 64, 1024, 2048, 1024,
                        16, 16, 0, 64, 0, 64, 0, TT, stream);
            softmax_k<<<16 * 1024, 256, 0, stream>>>(S);
            launch_gemm(false, S, vtb, yb, 1024, 64, 1024, 1024, 1024, 1024,
                        16, 16, 0, TT, 0, (long)DH_ * T_, 0, DH_, stream);
        }
        launch_gemm(true, y, wo_l, h, 2048, 1024, 1024, 1024, 1024, 1024,
                    1, 1, 0, 0, 0, 0, 0, 0, stream);

        // --- MLP ---
        rms_k<<<2048, 256, 0, stream>>>(h, cg2 + l * C_, a, 0, flag);
        launch_gemm(false, a, w1_l, u1, 2048, HFF_, 1024, 1024, 1024, HFF_,
                    1, 1, 0, 0, 0, 0, 0, 0, stream);
        launch_gemm(false, a, w2_l, u2, 2048, HFF_, 1024, 1024, 1024, HFF_,
                    1, 1, 0, 0, 0, 0, 0, 0, stream);
        silu_mul_k<<<22528, 256, 0, stream>>>(u1, u2);
        launch_gemm(true, u1, w3_l, h, 2048, 1024, HFF_, HFF_, HFF_, 1024,
                    1, 1, 0, 0, 0, 0, 0, 0, stream);
    }

    rms_k<<<2048, 256, 0, stream>>>(h, cgf, d_out, 1, flag);
}

// Round 5
// 1466.503 us; speedup vs baseline: 1.2181x; 1.2181x over previous
//
#include <hip/hip_runtime.h>
#include <hip/hip_bf16.h>

// LagLlama forward. fp32/bf16 input autodetect -> bf16 copies in ws.
// fp32 residual stream. Round 5 (= R4 + keyword fix): global_load_lds
// staging, fused qkv / w12 launches (batched-z), split-K wo/w3 via atomicAdd.
// B=2 T=1024 C=1024 NH=16 DH=64 L=4 HFF=2816

#define B_   2
#define T_   1024
#define C_   1024
#define NH_  16
#define DH_  64
#define L_   4
#define HFF_ 2816
#define EPS_ 1e-5f

typedef unsigned short u16;
typedef short bf16x8 __attribute__((ext_vector_type(8)));
typedef float f32x4 __attribute__((ext_vector_type(4)));

__device__ __forceinline__ float b2f(u16 u) {
    union { unsigned int i; float f; } v; v.i = ((unsigned int)u) << 16; return v.f;
}
__device__ __forceinline__ u16 f2b(float f) {
    union { unsigned int i; float f; } v; v.f = f;
    unsigned int r = (v.i + 0x7fff + ((v.i >> 16) & 1)) >> 16;
    return (u16)r;
}

// flag: 0 = inputs are bf16, 1 = inputs are fp32 (detected from x's raw bits)
__global__ void detect_k(const unsigned int* __restrict__ xw, int* __restrict__ flag)
{
    int tid = threadIdx.x;
    int cnt = 0;
#pragma unroll
    for (int i = 0; i < 4; ++i) {
        unsigned int w = xw[tid * 4 + i];
        unsigned int e = (w >> 7) & 0xFF;
        if (e >= 0x70 && e <= 0x87) cnt++;
    }
#pragma unroll
    for (int off = 32; off; off >>= 1) cnt += __shfl_down(cnt, off);
    if (tid == 0) flag[0] = (cnt > 128) ? 0 : 1;
}

// Relayout+convert: for chunk y (blockIdx.y), vec4-index i:
//   dst4[y*dstStrideV + dstOffV + i] = cvt(src4[y*perV + i])
__global__ void cvt_k(const void* __restrict__ src, u16* __restrict__ dst,
                      long perV, long dstStrideV, long dstOffV,
                      const int* __restrict__ flag)
{
    const int f = flag[0];
    long y = blockIdx.y;
    long i = (long)blockIdx.x * 256 + threadIdx.x;
    long stride = (long)gridDim.x * 256;
    for (; i < perV; i += stride) {
        long so = y * perV + i;
        long dj = y * dstStrideV + dstOffV + i;
        ushort4 o;
        if (f) {
            float4 v = ((const float4*)src)[so];
            o.x = f2b(v.x); o.y = f2b(v.y); o.z = f2b(v.z); o.w = f2b(v.w);
        } else {
            o = ((const ushort4*)src)[so];
        }
        ((ushort4*)dst)[dj] = o;
    }
}

// ---------------------------------------------------------------------------
// Batched GEMM: C[m,n] = sum_k A[m,k] * B[n,k]   (A: MxK lda, B: NxK ldb)
// MODE 0: write bf16 to Cb; z = batch (bb=z/nhDiv, hh=z%nhDiv), offsets
//         bb*s?b + hh*s?h (elements). N per sub-gemm; tail via clamp+mask.
// MODE 1: z = K-slice (kSplit slices); atomicAdd fp32 into Cf.
// M % 128 == 0; K (or K/kSplit) % 32 == 0.
// ---------------------------------------------------------------------------
template<int MODE>
__global__ __launch_bounds__(256, 2)
void gemm_bt(const u16* __restrict__ A, const u16* __restrict__ Bm,
             u16* __restrict__ Cb, float* __restrict__ Cf,
             int M, int N, int K, int lda, int ldb, int ldc,
             int nhDiv, long sAb, long sAh, long sBb, long sBh,
             long sCb, long sCh, int kSplit)
{
    __shared__ __align__(16) u16 tA[128 * 32];
    __shared__ __align__(16) u16 tB[128 * 32];

    const int z = blockIdx.z;
    int kBeg = 0, kEnd = K;
    const u16* Ab = A;
    const u16* Bb = Bm;
    long cOff = 0;
    if (MODE == 1) {
        int ks = K / kSplit;
        kBeg = z * ks; kEnd = kBeg + ks;
    } else {
        int bb = z / nhDiv;
        int hh = z - bb * nhDiv;
        Ab += bb * sAb + hh * sAh;
        Bb += bb * sBb + hh * sBh;
        cOff = bb * sCb + hh * sCh;
    }

    const int row0 = blockIdx.y * 128;
    const int col0 = blockIdx.x * 128;
    const int tid  = threadIdx.x;
    const int lane = tid & 63;
    const int wave = tid >> 6;
    const int wr = wave >> 1, wc = wave & 1;   // 2x2 waves of 64x64
    const int lrow = lane & 15;
    const int kg   = lane >> 4;

    f32x4 acc[4][4] = {};

    for (int k0 = kBeg; k0 < kEnd; k0 += 32) {
        __syncthreads();   // prior iter's LDS reads done before overwrite
#pragma unroll
        for (int i = 0; i < 2; ++i) {          // A tile: 512 x 16B chunks
            int chunk = i * 256 + tid;
            int r = chunk >> 2, cg = chunk & 3;
            const u16* ga = Ab + (long)(row0 + r) * lda + (k0 + cg * 8);
            u16* la = tA + (size_t)(i * 256 + wave * 64) * 8;  // wave-uniform
            __builtin_amdgcn_global_load_lds(
                (const __attribute__((address_space(1))) void*)ga,
                (__attribute__((address_space(3))) void*)la, 16, 0, 0);
        }
#pragma unroll
        for (int i = 0; i < 2; ++i) {          // B tile
            int chunk = i * 256 + tid;
            int r = chunk >> 2, cg = chunk & 3;
            int rB = col0 + r; if (rB > N - 1) rB = N - 1;   // N-tail clamp
            const u16* gb = Bb + (long)rB * ldb + (k0 + cg * 8);
            u16* lb = tB + (size_t)(i * 256 + wave * 64) * 8;
            __builtin_amdgcn_global_load_lds(
                (const __attribute__((address_space(1))) void*)gb,
                (__attribute__((address_space(3))) void*)lb, 16, 0, 0);
        }
        __syncthreads();

        bf16x8 af[4], bfr[4];
#pragma unroll
        for (int ti = 0; ti < 4; ++ti)
            af[ti] = *(const bf16x8*)&tA[(wr * 64 + ti * 16 + lrow) * 32 + kg * 8];
#pragma unroll
        for (int tj = 0; tj < 4; ++tj)
            bfr[tj] = *(const bf16x8*)&tB[(wc * 64 + tj * 16 + lrow) * 32 + kg * 8];
#pragma unroll
        for (int ti = 0; ti < 4; ++ti)
#pragma unroll
            for (int tj = 0; tj < 4; ++tj)
                acc[ti][tj] = __builtin_amdgcn_mfma_f32_16x16x32_bf16(
                    af[ti], bfr[tj], acc[ti][tj], 0, 0, 0);
    }

    // Epilogue: D[row = kg*4 + r][col = lane&15] per 16x16 tile.
    const int rbase = row0 + wr * 64;
    const int cbase = col0 + wc * 64 + lrow;
#pragma unroll
    for (int ti = 0; ti < 4; ++ti) {
#pragma unroll
        for (int r = 0; r < 4; ++r) {
            int row = rbase + ti * 16 + kg * 4 + r;
#pragma unroll
            for (int tj = 0; tj < 4; ++tj) {
                int col = cbase + tj * 16;
                if (col < N) {
                    long off = cOff + (long)row * ldc + col;
                    if (MODE == 0) Cb[off] = f2b(acc[ti][tj][r]);
                    else           atomicAdd(&Cf[off], acc[ti][tj][r]);
                }
            }
        }
    }
}

// h[bt,c] = sum_f x[bt,f] * w_in[c,f]   (K=9, fp32 out)
__global__ void input_proj_k(const u16* __restrict__ x, const u16* __restrict__ w,
                             float* __restrict__ h)
{
    int idx = blockIdx.x * 256 + threadIdx.x;      // 2M
    int bt = idx >> 10, c = idx & 1023;
    float s = 0.f;
#pragma unroll
    for (int f = 0; f < 9; ++f) s += b2f(x[bt * 9 + f]) * b2f(w[c * 9 + f]);
    h[idx] = s;
}

// out[row,:] = h * rsqrt(mean(h^2)+eps) * g.  isFinal&&flag -> fp32 out.
__global__ void rms_k(const float* __restrict__ h, const u16* __restrict__ g,
                      void* __restrict__ out, int isFinal,
                      const int* __restrict__ flag)
{
    __shared__ float red[8];
    const int row = blockIdx.x;
    const float* hr = h + (size_t)row * C_;
    float ss = 0.f;
    for (int c = threadIdx.x; c < C_; c += 256) { float v = hr[c]; ss += v * v; }
#pragma unroll
    for (int off = 32; off; off >>= 1) ss += __shfl_down(ss, off);
    int lane = threadIdx.x & 63, wave = threadIdx.x >> 6;
    if (lane == 0) red[wave] = ss;
    __syncthreads();
    if (threadIdx.x == 0)
        red[4] = rsqrtf((red[0] + red[1] + red[2] + red[3]) / (float)C_ + EPS_);
    __syncthreads();
    float r = red[4];
    const int f32out = isFinal && flag[0];
    for (int c = threadIdx.x; c < C_; c += 256) {
        float val = hr[c] * r * b2f(g[c]);
        size_t o = (size_t)row * C_ + c;
        if (f32out) ((float*)out)[o] = val;
        else        ((u16*)out)[o]   = f2b(val);
    }
}

// RoPE in place on qkv[b,t,:]: q cols 0..1023, k cols 1024..2047 (ld 3072)
__global__ void rope_k(u16* __restrict__ qkv)
{
    int idx = blockIdx.x * 256 + threadIdx.x;      // B*T*NH*32 = 1M
    int i = idx & 31;
    int hh = (idx >> 5) & 15;
    int t = (idx >> 9) & 1023;
    int b = idx >> 19;
    float invf = powf(10000.0f, -(float)i / 32.0f);
    float fr = (float)t * invf;
    float cf = cosf(fr), sf = sinf(fr);

    size_t base = (size_t)(b * 1024 + t) * 3072 + hh * 64 + i;
    float x1 = b2f(qkv[base]), x2 = b2f(qkv[base + 32]);
    qkv[base]      = f2b(x1 * cf - x2 * sf);
    qkv[base + 32] = f2b(x2 * cf + x1 * sf);

    size_t kb = base + 1024;
    x1 = b2f(qkv[kb]); x2 = b2f(qkv[kb + 32]);
    qkv[kb]      = f2b(x1 * cf - x2 * sf);
    qkv[kb + 32] = f2b(x2 * cf + x1 * sf);
}

// vt[b,h,d,s] = qkv[b,s, 2048 + h*64 + d]
__global__ void vtrans_k(const u16* __restrict__ qkv, u16* __restrict__ vt)
{
    int idx = blockIdx.x * 256 + threadIdx.x;      // 2M
    int s = idx & 1023;
    int d = (idx >> 10) & 63;
    int hh = (idx >> 16) & 15;
    int b = idx >> 20;
    vt[idx] = qkv[(size_t)(b * 1024 + s) * 3072 + 2048 + hh * 64 + d];
}

// causal softmax row (z,t) in place on bf16 scores; scale=0.125 folded in.
__global__ void softmax_k(u16* __restrict__ S)
{
    __shared__ float red[8];
    const int t = blockIdx.x & 1023;
    const int z = blockIdx.x >> 10;
    u16* row = S + ((size_t)z << 20) + ((size_t)t << 10);
    const int n = t + 1;
    const int tid = threadIdx.x;
    const int lane = tid & 63, wave = tid >> 6;

    float mx = -1e30f;
    for (int c = tid; c < n; c += 256) mx = fmaxf(mx, 0.125f * b2f(row[c]));
#pragma unroll
    for (int off = 32; off; off >>= 1) mx = fmaxf(mx, __shfl_down(mx, off));
    if (lane == 0) red[wave] = mx;
    __syncthreads();
    if (tid == 0) red[4] = fmaxf(fmaxf(red[0], red[1]), fmaxf(red[2], red[3]));
    __syncthreads();
    const float M = red[4];

    float sum = 0.f;
    for (int c = tid; c < n; c += 256) sum += __expf(0.125f * b2f(row[c]) - M);
#pragma unroll
    for (int off = 32; off; off >>= 1) sum += __shfl_down(sum, off);
    if (lane == 0) red[wave] = sum;
    __syncthreads();
    if (tid == 0) red[5] = red[0] + red[1] + red[2] + red[3];
    __syncthreads();
    const float inv = 1.0f / red[5];

    for (int c = tid; c < 1024; c += 256) {
        float p = (c < n) ? __expf(0.125f * b2f(row[c]) - M) * inv : 0.f;
        row[c] = f2b(p);
    }
}

// u1 = silu(u1) * u2
__global__ void silu_mul_k(u16* __restrict__ u1, const u16* __restrict__ u2)
{
    size_t idx = (size_t)blockIdx.x * 256 + threadIdx.x;   // 2048*2816
    float a = b2f(u1[idx]);
    float m = a / (1.f + __expf(-a));
    u1[idx] = f2b(m * b2f(u2[idx]));
}

// ---------------------------------------------------------------------------
static inline void launch_gemm(bool add, const u16* A, const u16* Bm, void* C,
                               int M, int N, int K, int lda, int ldb, int ldc,
                               int zdim, int nhDiv,
                               long sAb, long sAh, long sBb, long sBh,
                               long sCb, long sCh, int kSplit, hipStream_t stream)
{
    dim3 g((N + 127) / 128, M / 128, zdim);
    if (add)
        gemm_bt<1><<<g, 256, 0, stream>>>(A, Bm, nullptr, (float*)C,
            M, N, K, lda, ldb, ldc, nhDiv, sAb, sAh, sBb, sBh, sCb, sCh, kSplit);
    else
        gemm_bt<0><<<g, 256, 0, stream>>>(A, Bm, (u16*)C, nullptr,
            M, N, K, lda, ldb, ldc, nhDiv, sAb, sAh, sBb, sBh, sCb, sCh, kSplit);
}

static inline void launch_cvt(const void* src, u16* dst, long perV,
                              long dstStrideV, long dstOffV, int chunks,
                              const int* flag, hipStream_t stream)
{
    long bx = (perV + 255) / 256; if (bx > 512) bx = 512;
    dim3 g((unsigned)bx, (unsigned)chunks, 1);
    cvt_k<<<g, 256, 0, stream>>>(src, dst, perV, dstStrideV, dstOffV, flag);
}

extern "C" void kernel_launch(void* const* d_in, const int* in_sizes, int n_in,
                              void* d_out, int out_size, void* d_ws, size_t ws_size,
                              hipStream_t stream)
{
    char* w = (char*)d_ws;
    float* h   = (float*)w;                          // [0,8) MB fp32 residual
    u16* a     = (u16*)(w + (8u  << 20));            // [8,12)
    u16* qkv   = (u16*)(w + (12u << 20));            // [12,24)  [2048][3072]
    u16* vt    = (u16*)(w + (24u << 20));            // [24,28)
    u16* y     = (u16*)(w + (28u << 20));            // [28,32)
    u16* S     = (u16*)(w + (32u << 20));            // [32,64)  16 heads x 1M
    u16* u1    = S;                                  // MLP overlaps S lifetime
    u16* u2    = S + (size_t)2048 * HFF_;

    // bf16 weight copies (relayout) above 64 MB — same footprint as R3.
    size_t off = (size_t)64 << 20;
    u16* cx    = (u16*)(w + off); off += ((size_t)B_*T_*9*2   + 255) & ~(size_t)255;
    u16* cwin  = (u16*)(w + off); off += ((size_t)C_*9*2      + 255) & ~(size_t)255;
    u16* cwqkv = (u16*)(w + off); off += (size_t)L_*3072*1024*2;   // fused q|k|v
    u16* cwo   = (u16*)(w + off); off += (size_t)L_*C_*C_*2;
    u16* cw12  = (u16*)(w + off); off += (size_t)L_*2*HFF_*C_*2;   // fused w1|w2
    u16* cw3   = (u16*)(w + off); off += (size_t)L_*C_*HFF_*2;
    u16* cg1   = (u16*)(w + off); off += ((size_t)L_*C_*2 + 255) & ~(size_t)255;
    u16* cg2   = (u16*)(w + off); off += ((size_t)L_*C_*2 + 255) & ~(size_t)255;
    u16* cgf   = (u16*)(w + off); off += ((size_t)C_*2    + 255) & ~(size_t)255;
    int* flag  = (int*)(w + off);

    detect_k<<<1, 64, 0, stream>>>((const unsigned int*)d_in[0], flag);

    const long CCv  = (long)C_ * C_ / 4;        // 262144
    const long HCv  = (long)HFF_ * C_ / 4;      // 720896
    launch_cvt(d_in[0],  cx,    (long)B_*T_*9/4, 0, 0, 1, flag, stream);
    launch_cvt(d_in[1],  cwin,  (long)C_*9/4,    0, 0, 1, flag, stream);
    launch_cvt(d_in[2],  cwqkv, CCv,   3*CCv, 0,     L_, flag, stream);  // wq
    launch_cvt(d_in[3],  cwqkv, 2*CCv, 3*CCv, CCv,   L_, flag, stream);  // wkv
    launch_cvt(d_in[4],  cwo,   CCv,   CCv,   0,     L_, flag, stream);
    launch_cvt(d_in[5],  cw12,  HCv,   2*HCv, 0,     L_, flag, stream);  // w1
    launch_cvt(d_in[6],  cw12,  HCv,   2*HCv, HCv,   L_, flag, stream);  // w2
    launch_cvt(d_in[7],  cw3,   HCv,   HCv,   0,     L_, flag, stream);
    launch_cvt(d_in[8],  cg1,   (long)L_*C_/4, 0, 0, 1, flag, stream);
    launch_cvt(d_in[9],  cg2,   (long)L_*C_/4, 0, 0, 1, flag, stream);
    launch_cvt(d_in[10], cgf,   (long)C_/4,    0, 0, 1, flag, stream);

    const long TC  = (long)T_ * C_;      // 1M
    const long TT  = (long)T_ * T_;      // 1M
    const long TQ  = (long)T_ * 3072;    // qkv row-block per batch

    input_proj_k<<<8192, 256, 0, stream>>>(cx, cwin, h);

    for (int l = 0; l < L_; ++l) {
        const u16* wqkv_l = cwqkv + (size_t)l * 3072 * 1024;
        const u16* wo_l   = cwo   + (size_t)l * C_ * C_;
        const u16* w12_l  = cw12  + (size_t)l * 2 * HFF_ * C_;
        const u16* w3_l   = cw3   + (size_t)l * C_ * HFF_;

        // --- attention ---
        rms_k<<<2048, 256, 0, stream>>>(h, cg1 + l * C_, a, 0, flag);
        // qkv[2048][3072] = a @ [wq|wk|wv]^T   (z=3 chunks of N=1024)
        launch_gemm(false, a, wqkv_l, qkv, 2048, 1024, 1024, 1024, 1024, 3072,
                    3, 3, 0, 0, 0, (long)C_*C_, 0, 1024, 1, stream);
        rope_k<<<4096, 256, 0, stream>>>(qkv);
        vtrans_k<<<8192, 256, 0, stream>>>(qkv, vt);

        for (int b = 0; b < B_; ++b) {    // per-batch attention (S = 32 MB)
            const u16* qb = qkv + (size_t)b * TQ;          // q cols 0..1023
            const u16* kb = qb + 1024;                     // k cols
            const u16* vtb = vt + (size_t)b * NH_ * DH_ * T_;
            u16* yb        = y  + (size_t)b * TC;
            // S[h,t,s] = q . k   (z = head, K=64)
            launch_gemm(false, qb, kb, S, 1024, 1024, 64, 3072, 3072, 1024,
                        16, 16, 0, 64, 0, 64, 0, TT, 1, stream);
            softmax_k<<<16 * 1024, 256, 0, stream>>>(S);
            // y[t, h*64+d] = P . V^T   (N=64)
            launch_gemm(false, S, vtb, yb, 1024, 64, 1024, 1024, 1024, 1024,
                        16, 16, 0, TT, 0, (long)DH_*T_, 0, DH_, 1, stream);
        }
        // h += y @ wo^T   (split-K x4)
        launch_gemm(true, y, wo_l, h, 2048, 1024, 1024, 1024, 1024, 1024,
                    4, 1, 0, 0, 0, 0, 0, 0, 4, stream);

        // --- MLP ---
        rms_k<<<2048, 256, 0, stream>>>(h, cg2 + l * C_, a, 0, flag);
        // [u1|u2] = a @ [w1|w2]^T   (z=2 chunks of N=2816)
        launch_gemm(false, a, w12_l, u1, 2048, HFF_, 1024, 1024, 1024, HFF_,
                    2, 2, 0, 0, 0, (long)HFF_*C_, 0, (long)2048*HFF_, 1, stream);
        silu_mul_k<<<22528, 256, 0, stream>>>(u1, u2);
        // h += u1 @ w3^T   (split-K x4, K=2816 -> 704 per slice)
        launch_gemm(true, u1, w3_l, h, 2048, 1024, HFF_, HFF_, HFF_, 1024,
                    4, 1, 0, 0, 0, 0, 0, 0, 4, stream);
    }

    rms_k<<<2048, 256, 0, stream>>>(h, cgf, d_out, 1, flag);
}